// Round 2
// baseline (135.817 us; speedup 1.0000x reference)
//
#include <hip/hip_runtime.h>
#include <math.h>

#define B_N 4096
#define H_N 256
#define I_N 32
#define G3  768
#define W2_ELEMS (I_N * H_N * G3)   // 6291456 floats

// workspace layout (bytes)
#define WS_IDX     0            // 4096 ints
#define WS_COUNTS  16384        // 32 ints
#define WS_CURSOR  16512        // 32 ints
#define WS_OFFS    16640        // 33 ints
#define WS_NITEMS  16776        // 1 int
#define WS_ITEMS   16784        // up to 288+ ints
#define WS_SLOTS   20480        // 128 ints (BM=64 plan, XCD-bucketed)
#define WS_SORTED  32768        // 4096 ints
#define WS_W2      65536        // 24 MB fp32
#define WS_REC     (WS_W2 + (size_t)W2_ELEMS * 4)          // 12 MB
#define WS_FULL    (WS_REC + (size_t)B_N * G3 * 4)
#define WS_MID     ((size_t)WS_REC)

#define NSLOT   128
#define SLOTCAP 16

__device__ __forceinline__ float sigm(float x) { return 1.0f / (1.0f + expf(-x)); }

// --- phase B1: one-hot -> expert index, histogram -------------------------
__global__ void k_idx_count(const float* __restrict__ inp, int* __restrict__ idx_arr,
                            int* __restrict__ counts) {
    int b = blockIdx.x * blockDim.x + threadIdx.x;
    if (b >= B_N) return;
    const float4* p = (const float4*)(inp + b * I_N);
    int idx = 0;
#pragma unroll
    for (int k = 0; k < 8; ++k) {
        float4 v = p[k];
        if (v.x > 0.5f) idx = k * 4 + 0;
        if (v.y > 0.5f) idx = k * 4 + 1;
        if (v.z > 0.5f) idx = k * 4 + 2;
        if (v.w > 0.5f) idx = k * 4 + 3;
    }
    idx_arr[b] = idx;
    atomicAdd(counts + idx, 1);
}

// --- phase B2: prefix offsets + both work plans (tiny, serial) ------------
// items: BM=16 chunks (legacy path).  slots: BM=64 chunks, XCD-affine
// (expert e -> slot index == e mod 8, so same-expert blocks share an XCD L2).
__global__ void k_plan(const int* __restrict__ counts, int* __restrict__ offs,
                       int* __restrict__ cursor, int* __restrict__ nitems,
                       int* __restrict__ items, int* __restrict__ slots) {
    if (threadIdx.x != 0 || blockIdx.x != 0) return;
    int bcur[8];
#pragma unroll
    for (int b = 0; b < 8; ++b) bcur[b] = 0;
    for (int s = 0; s < NSLOT; ++s) slots[s] = -1;
    int ovf[96]; int novf = 0;
    int off = 0, nit = 0;
    for (int e = 0; e < I_N; ++e) {
        offs[e] = off;
        int c = counts[e];
        off += c;
        cursor[e] = 0;
        int nch16 = (c + 15) >> 4;
        for (int ch = 0; ch < nch16; ++ch) items[nit++] = (e << 16) | ch;
        int nch64 = (c + 63) >> 6;
        int bkt = e & 7;
        for (int ch = 0; ch < nch64; ++ch) {
            int j = bcur[bkt];
            if (j < SLOTCAP) { slots[bkt + 8 * j] = (e << 16) | ch; bcur[bkt] = j + 1; }
            else if (novf < 96) ovf[novf++] = (e << 16) | ch;
        }
    }
    offs[I_N] = off;
    *nitems = nit;
    int p = 0;
    for (int k = 0; k < novf; ++k) {
        while (p < NSLOT && slots[p] >= 0) p++;
        if (p < NSLOT) slots[p++] = ovf[k];
    }
}

// --- phase B3: scatter batch ids into expert-sorted order -----------------
__global__ void k_scatter(const int* __restrict__ idx_arr, const int* __restrict__ offs,
                          int* __restrict__ cursor, int* __restrict__ sorted) {
    int b = blockIdx.x * blockDim.x + threadIdx.x;
    if (b >= B_N) return;
    int i = idx_arr[b];
    int pos = atomicAdd(cursor + i, 1);
    sorted[offs[i] + pos] = b;
}

// --- phase R: repack W[g][h][i] -> W2[i][h][g] (coalesced both sides) -----
__global__ void k_repack(const float* __restrict__ w, float* __restrict__ w2) {
    __shared__ float tile[64][33];
    int gc = blockIdx.x;          // 0..11 (g chunk of 64)
    int h  = blockIdx.y;          // 0..255
    int g0 = gc * 64;
    int t = threadIdx.x;
#pragma unroll
    for (int k = 0; k < 8; ++k) {
        int e = t + k * 256;
        int i = e & 31, dg = e >> 5;
        tile[dg][i] = w[((g0 + dg) * H_N + h) * I_N + i];
    }
    __syncthreads();
#pragma unroll
    for (int k = 0; k < 8; ++k) {
        int f = t + k * 256;
        int dg = f & 63, ii = f >> 6;
        w2[(ii * H_N + h) * G3 + g0 + dg] = tile[dg][ii];
    }
}

// --- phase C (new): 64x64 tiled GEMM, 1-wave blocks, 8x8 frags ------------
#define KT  32
#define LDT 68   // padded leading dim (floats); 68*4B keeps b128 alignment, spreads banks
__global__ __launch_bounds__(64) void k_gemm64(
    const float* __restrict__ w2, const float* __restrict__ hx,
    const int* __restrict__ sorted, const int* __restrict__ offs,
    const int* __restrict__ counts, const int* __restrict__ slots,
    float* __restrict__ rec) {
    int item = slots[blockIdx.x];
    if (item < 0) return;
    int ex = item >> 16, ch = item & 0xffff;
    int base = offs[ex] + ch * 64;
    int M = counts[ex] - ch * 64; if (M > 64) M = 64;
    int n0 = blockIdx.y * 64;
    int tid = threadIdx.x;

    __shared__ float As[KT][LDT];
    __shared__ float Bs[KT][LDT];

    bool valid = tid < M;
    int brow = valid ? sorted[base + tid] : 0;
    const float* arow = hx + brow * H_N;

    int tx = tid & 7, ty = tid >> 3;
    float acc[8][8];
#pragma unroll
    for (int i = 0; i < 8; ++i)
#pragma unroll
        for (int j = 0; j < 8; ++j) acc[i][j] = 0.f;

    const float* bsrc = w2 + (size_t)ex * (H_N * G3) + n0;

    for (int k0 = 0; k0 < H_N; k0 += KT) {
        // stage A: thread stages its own hx row (contiguous 128B per lane), transposed
        if (valid) {
#pragma unroll
            for (int r = 0; r < 8; ++r) {
                float4 v = *(const float4*)(arow + k0 + r * 4);
                As[r * 4 + 0][tid] = v.x;
                As[r * 4 + 1][tid] = v.y;
                As[r * 4 + 2][tid] = v.z;
                As[r * 4 + 3][tid] = v.w;
            }
        } else {
#pragma unroll
            for (int r = 0; r < KT; ++r) As[r][tid] = 0.f;
        }
        // stage B: 32k x 64n tile, coalesced 256B rows
#pragma unroll
        for (int r = 0; r < 8; ++r) {
            int q = tid + r * 64;          // 0..511
            int kk = q >> 4;               // 0..31
            int n4 = (q & 15) << 2;        // 0..60
            float4 v = *(const float4*)(bsrc + (size_t)(k0 + kk) * G3 + n4);
            *(float4*)&Bs[kk][n4] = v;
        }
        __syncthreads();
#pragma unroll 8
        for (int kk = 0; kk < KT; ++kk) {
            float4 a0 = *(const float4*)&As[kk][ty * 8];
            float4 a1 = *(const float4*)&As[kk][ty * 8 + 4];
            float4 b0 = *(const float4*)&Bs[kk][tx * 8];
            float4 b1 = *(const float4*)&Bs[kk][tx * 8 + 4];
            float am[8] = {a0.x, a0.y, a0.z, a0.w, a1.x, a1.y, a1.z, a1.w};
            float bn[8] = {b0.x, b0.y, b0.z, b0.w, b1.x, b1.y, b1.z, b1.w};
#pragma unroll
            for (int i = 0; i < 8; ++i)
#pragma unroll
                for (int j = 0; j < 8; ++j)
                    acc[i][j] = fmaf(am[i], bn[j], acc[i][j]);
        }
        __syncthreads();
    }
    // write rec in sorted-position order
#pragma unroll
    for (int i = 0; i < 8; ++i) {
        int m = ty * 8 + i;
        if (m < M) {
            float* dst = rec + (size_t)(base + m) * G3 + n0 + tx * 8;
            float4 w0 = {acc[i][0], acc[i][1], acc[i][2], acc[i][3]};
            float4 w1 = {acc[i][4], acc[i][5], acc[i][6], acc[i][7]};
            *(float4*)dst = w0;
            *(float4*)(dst + 4) = w1;
        }
    }
}

// --- phase E: fused GRU gate epilogue -------------------------------------
__global__ __launch_bounds__(256) void k_epi(
    const float* __restrict__ rec, const float* __restrict__ hx,
    const float* __restrict__ b_ih, const float* __restrict__ b_hh,
    const int* __restrict__ sorted, const int* __restrict__ idx_arr,
    float* __restrict__ out) {
    int p = blockIdx.x;
    int t = threadIdx.x;
    int b = sorted[p];
    int e = idx_arr[b];
    const float* rp = rec + (size_t)p * G3;
    float a0 = rp[t], a1 = rp[256 + t], a2 = rp[512 + t];
    float bi0 = b_ih[t * I_N + e],         bh0 = b_hh[t * I_N + e];
    float bi1 = b_ih[(256 + t) * I_N + e], bh1 = b_hh[(256 + t) * I_N + e];
    float bi2 = b_ih[(512 + t) * I_N + e], bh2 = b_hh[(512 + t) * I_N + e];
    float xv = hx[b * H_N + t];
    float r = sigm(bi0 + a0 + bh0);
    float u = sigm(bi1 + a1 + bh1);
    float n = tanhf(bi2 + r * (a2 + bh2));
    out[b * H_N + t] = u * xv + (1.0f - u) * n;
}

// --- legacy phase C (BM=16 broadcast GEMM), mid-tier ws fallback ----------
__global__ __launch_bounds__(256) void k_gemm(
    const float* __restrict__ w2, const float* __restrict__ hx,
    const float* __restrict__ b_ih, const float* __restrict__ b_hh,
    const int* __restrict__ sorted, const int* __restrict__ offs,
    const int* __restrict__ counts, const int* __restrict__ nitems,
    const int* __restrict__ items, float* __restrict__ out) {
    int bid = blockIdx.x;
    if (bid >= *nitems) return;
    int item = items[bid];
    int ex = item >> 16, ch = item & 0xffff;
    int base = offs[ex] + ch * 16;
    int cnt = counts[ex];
    int M = min(16, cnt - ch * 16);
    int t = threadIdx.x;

    __shared__ float hxs[16][H_N];
    __shared__ int bids[16];
    if (t < 16) bids[t] = (t < M) ? sorted[base + t] : -1;
    __syncthreads();
#pragma unroll
    for (int m = 0; m < 16; ++m) {
        int b = bids[m];
        hxs[m][t] = (b >= 0) ? hx[b * H_N + t] : 0.0f;
    }
    __syncthreads();

    float acc0[16], acc1[16], acc2[16];
#pragma unroll
    for (int m = 0; m < 16; ++m) { acc0[m] = 0.f; acc1[m] = 0.f; acc2[m] = 0.f; }

    const float* wp = w2 + ex * (H_N * G3) + t;
    for (int h = 0; h < H_N; h += 4) {
        float w0[4], w1[4], w2r[4];
#pragma unroll
        for (int k = 0; k < 4; ++k) {
            w0[k] = wp[0]; w1[k] = wp[256]; w2r[k] = wp[512];
            wp += G3;
        }
#pragma unroll
        for (int m = 0; m < 16; ++m) {
            float4 x = *(const float4*)(&hxs[m][h]);
            acc0[m] = fmaf(w0[0], x.x, acc0[m]);
            acc1[m] = fmaf(w1[0], x.x, acc1[m]);
            acc2[m] = fmaf(w2r[0], x.x, acc2[m]);
            acc0[m] = fmaf(w0[1], x.y, acc0[m]);
            acc1[m] = fmaf(w1[1], x.y, acc1[m]);
            acc2[m] = fmaf(w2r[1], x.y, acc2[m]);
            acc0[m] = fmaf(w0[2], x.z, acc0[m]);
            acc1[m] = fmaf(w1[2], x.z, acc1[m]);
            acc2[m] = fmaf(w2r[2], x.z, acc2[m]);
            acc0[m] = fmaf(w0[3], x.w, acc0[m]);
            acc1[m] = fmaf(w1[3], x.w, acc1[m]);
            acc2[m] = fmaf(w2r[3], x.w, acc2[m]);
        }
    }

    float bi0 = b_ih[t * I_N + ex], bi1 = b_ih[(256 + t) * I_N + ex], bi2 = b_ih[(512 + t) * I_N + ex];
    float bh0 = b_hh[t * I_N + ex], bh1 = b_hh[(256 + t) * I_N + ex], bh2 = b_hh[(512 + t) * I_N + ex];
    for (int m = 0; m < M; ++m) {
        int b = bids[m];
        float xv = hxs[m][t];
        float r = sigm(bi0 + acc0[m] + bh0);
        float u = sigm(bi1 + acc1[m] + bh1);
        float n = tanhf(bi2 + r * (acc2[m] + bh2));
        out[b * H_N + t] = u * xv + (1.0f - u) * n;
    }
}

// --- fallback: correct but slow, if ws too small --------------------------
__global__ void k_naive(const float* __restrict__ inp, const float* __restrict__ hx,
                        const float* __restrict__ w, const float* __restrict__ b_ih,
                        const float* __restrict__ b_hh, float* __restrict__ out) {
    int b = blockIdx.x;
    int t = threadIdx.x;
    __shared__ float sx[H_N];
    __shared__ int sidx;
    if (t == 0) {
        int idx = 0;
        for (int i = 0; i < I_N; ++i)
            if (inp[b * I_N + i] > 0.5f) idx = i;
        sidx = idx;
    }
    sx[t] = hx[b * H_N + t];
    __syncthreads();
    int i = sidx;
    float a0 = 0.f, a1 = 0.f, a2 = 0.f;
    for (int h = 0; h < H_N; ++h) {
        float xv = sx[h];
        a0 = fmaf(w[(t * H_N + h) * I_N + i], xv, a0);
        a1 = fmaf(w[((256 + t) * H_N + h) * I_N + i], xv, a1);
        a2 = fmaf(w[((512 + t) * H_N + h) * I_N + i], xv, a2);
    }
    float r = sigm(b_ih[t * I_N + i] + a0 + b_hh[t * I_N + i]);
    float u = sigm(b_ih[(256 + t) * I_N + i] + a1 + b_hh[(256 + t) * I_N + i]);
    float n = tanhf(b_ih[(512 + t) * I_N + i] + r * (a2 + b_hh[(512 + t) * I_N + i]));
    out[b * H_N + t] = u * sx[t] + (1.0f - u) * n;
}

extern "C" void kernel_launch(void* const* d_in, const int* in_sizes, int n_in,
                              void* d_out, int out_size, void* d_ws, size_t ws_size,
                              hipStream_t stream) {
    const float* inp  = (const float*)d_in[0];
    const float* hx   = (const float*)d_in[1];
    const float* w    = (const float*)d_in[2];
    const float* b_ih = (const float*)d_in[3];
    const float* b_hh = (const float*)d_in[4];
    float* out = (float*)d_out;

    if (ws_size < WS_MID) {
        k_naive<<<B_N, H_N, 0, stream>>>(inp, hx, w, b_ih, b_hh, out);
        return;
    }

    char* ws = (char*)d_ws;
    int* idx_arr = (int*)(ws + WS_IDX);
    int* counts  = (int*)(ws + WS_COUNTS);
    int* cursor  = (int*)(ws + WS_CURSOR);
    int* offs    = (int*)(ws + WS_OFFS);
    int* nitems  = (int*)(ws + WS_NITEMS);
    int* items   = (int*)(ws + WS_ITEMS);
    int* slots   = (int*)(ws + WS_SLOTS);
    int* sorted  = (int*)(ws + WS_SORTED);
    float* w2    = (float*)(ws + WS_W2);
    float* rec   = (float*)(ws + WS_REC);

    hipMemsetAsync(counts, 0, 128, stream);
    k_idx_count<<<B_N / 256, 256, 0, stream>>>(inp, idx_arr, counts);
    k_plan<<<1, 64, 0, stream>>>(counts, offs, cursor, nitems, items, slots);
    k_scatter<<<B_N / 256, 256, 0, stream>>>(idx_arr, offs, cursor, sorted);
    k_repack<<<dim3(12, 256), 256, 0, stream>>>(w, w2);

    if (ws_size >= WS_FULL) {
        k_gemm64<<<dim3(NSLOT, 12), 64, 0, stream>>>(w2, hx, sorted, offs, counts, slots, rec);
        k_epi<<<B_N, 256, 0, stream>>>(rec, hx, b_ih, b_hh, sorted, idx_arr, out);
    } else {
        k_gemm<<<288, 256, 0, stream>>>(w2, hx, b_ih, b_hh, sorted, offs, counts, nitems, items, out);
    }
}

// Round 3
// 79.751 us; speedup vs baseline: 1.7030x; 1.7030x over previous
//
#include <hip/hip_runtime.h>
#include <math.h>

#define B_N 4096
#define H_N 256
#define I_N 32
#define G3  768

// ---- workspace layout (bytes) ----
#define WS_IDX     0               // 4096 ints
#define WS_CURSOR  16384           // 32 ints
#define WS_NITEMS  16512           // 1 int
#define WS_ITEMS   16640           // 288 ints
#define WS_SORTED  18432           // 4096 ints
#define WS_B4      34816           // 32*256 float4 = 128 KB
#define WS_HXH     165888          // 4096*256 bf16 = 2 MB
#define WS_HXL     2263040         // 2 MB
#define WS_W3H     4360192         // 32*768*256 bf16 = 12 MB
#define WS_W3L     16943104        // 12 MB
#define WS_NEEDED  29526016

typedef __attribute__((ext_vector_type(8))) short bf16x8_t;
typedef __attribute__((ext_vector_type(4))) float f32x4_t;

__device__ __forceinline__ float sigm(float x) { return 1.0f / (1.0f + expf(-x)); }

__device__ __forceinline__ unsigned short bf16r(float f) {
    union { float f; unsigned u; } x; x.f = f;
    unsigned r = (x.u + 0x7fffu + ((x.u >> 16) & 1u)) >> 16;
    return (unsigned short)r;
}
__device__ __forceinline__ float bf16f(unsigned short h) {
    union { unsigned u; float f; } x; x.u = ((unsigned)h) << 16;
    return x.f;
}

// --- one-hot -> expert index ----------------------------------------------
__global__ void k_idx(const float* __restrict__ inp, int* __restrict__ idx_arr) {
    int b = blockIdx.x * blockDim.x + threadIdx.x;
    if (b >= B_N) return;
    const float4* p = (const float4*)(inp + b * I_N);
    int idx = 0;
#pragma unroll
    for (int k = 0; k < 8; ++k) {
        float4 v = p[k];
        if (v.x > 0.5f) idx = k * 4 + 0;
        if (v.y > 0.5f) idx = k * 4 + 1;
        if (v.z > 0.5f) idx = k * 4 + 2;
        if (v.w > 0.5f) idx = k * 4 + 3;
    }
    idx_arr[b] = idx;
}

// --- histogram + prefix + chunk plan (1 block, parallel) ------------------
// item = (e<<20) | (base<<5) | M   (base = start pos in sorted[], M<=16)
__global__ void k_plan(const int* __restrict__ idx_arr, int* __restrict__ cursor,
                       int* __restrict__ nitems, int* __restrict__ items) {
    __shared__ int hist[32], offs_l[32];
    __shared__ int nit;
    int t = threadIdx.x;
    if (t < 32) hist[t] = 0;
    if (t == 0) nit = 0;
    __syncthreads();
    for (int i = t; i < B_N; i += 512) atomicAdd(&hist[idx_arr[i]], 1);
    __syncthreads();
    if (t == 0) {
        int run = 0;
        for (int e = 0; e < 32; ++e) { offs_l[e] = run; run += hist[e]; }
    }
    __syncthreads();
    if (t < 32) cursor[t] = offs_l[t];
    for (int c = t; c < 32 * 256; c += 512) {
        int e = c >> 8, ch = c & 255;
        int cnt = hist[e];
        if (ch * 16 < cnt) {
            int M = cnt - ch * 16; if (M > 16) M = 16;
            int base = offs_l[e] + ch * 16;
            int p = atomicAdd(&nit, 1);
            items[p] = (e << 20) | (base << 5) | M;
        }
    }
    __syncthreads();
    if (t == 0) *nitems = nit;
}

// --- scatter batch ids into expert-sorted order ---------------------------
__global__ void k_scatter(const int* __restrict__ idx_arr, int* __restrict__ cursor,
                          int* __restrict__ sorted) {
    int b = blockIdx.x * blockDim.x + threadIdx.x;
    if (b >= B_N) return;
    int i = idx_arr[b];
    int pos = atomicAdd(cursor + i, 1);
    sorted[pos] = b;
}

// --- split hx into bf16 hi/lo ---------------------------------------------
__global__ void k_split_hx(const float* __restrict__ hx, unsigned short* __restrict__ hxh,
                           unsigned short* __restrict__ hxl) {
    int i = (blockIdx.x * 256 + threadIdx.x) * 4;
    float4 v = *(const float4*)(hx + i);
    union { unsigned short us[4]; uint2 v; } ph, pl;
    float f[4] = {v.x, v.y, v.z, v.w};
#pragma unroll
    for (int c = 0; c < 4; ++c) {
        unsigned short h = bf16r(f[c]);
        ph.us[c] = h;
        pl.us[c] = bf16r(f[c] - bf16f(h));
    }
    *(uint2*)(hxh + i) = ph.v;
    *(uint2*)(hxl + i) = pl.v;
}

// --- bias precompute: b4[e][t] = {r_sum, u_sum, n_ih, n_hh} ---------------
__global__ void k_bias4(const float* __restrict__ b_ih, const float* __restrict__ b_hh,
                        float4* __restrict__ b4) {
    int t = threadIdx.x;
    int e = t & 31;
    int tt = blockIdx.x * 8 + (t >> 5);
    float r = b_ih[(0 * 256 + tt) * 32 + e] + b_hh[(0 * 256 + tt) * 32 + e];
    float u = b_ih[(256 + tt) * 32 + e] + b_hh[(256 + tt) * 32 + e];
    float ni = b_ih[(512 + tt) * 32 + e];
    float nh = b_hh[(512 + tt) * 32 + e];
    float4 o = {r, u, ni, nh};
    b4[e * 256 + tt] = o;
}

// --- repack w[g][h][e] -> w3{h,l}[e][n=g][k=h], bf16 hi/lo ----------------
__global__ __launch_bounds__(256) void k_repack(const float* __restrict__ w,
                                                unsigned short* __restrict__ w3h,
                                                unsigned short* __restrict__ w3l) {
    __shared__ float tl[16928];   // [dg:16][hh:32][e:32], flat = dg*1058 + hh*33 + e
    int g0 = blockIdx.x * 16, h0 = blockIdx.y * 32;
    int t = threadIdx.x;
#pragma unroll
    for (int it = 0; it < 16; ++it) {
        int f4 = it * 256 + t;               // 0..4095
        int f = f4 * 4;
        int dg = f >> 10, hh = (f >> 5) & 31, e0 = f & 31;
        float4 v = *(const float4*)(w + ((size_t)(g0 + dg) * 256 + h0 + hh) * 32 + e0);
        int bse = dg * 1058 + hh * 33 + e0;
        tl[bse + 0] = v.x; tl[bse + 1] = v.y; tl[bse + 2] = v.z; tl[bse + 3] = v.w;
    }
    __syncthreads();
#pragma unroll
    for (int a = 0; a < 8; ++a) {
        int idx = a * 256 + t;               // 0..2047
        int q = idx & 3, dg = (idx >> 2) & 15, e = idx >> 6;
        union { unsigned short us[8]; uint4 v; } hi, lo;
#pragma unroll
        for (int jj = 0; jj < 8; ++jj) {
            float f = tl[dg * 1058 + (q * 8 + jj) * 33 + e];
            unsigned short h = bf16r(f);
            hi.us[jj] = h;
            lo.us[jj] = bf16r(f - bf16f(h));
        }
        size_t off = ((size_t)e * G3 + g0 + dg) * 256 + h0 + q * 8;
        *(uint4*)(w3h + off) = hi.v;
        *(uint4*)(w3l + off) = lo.v;
    }
}

// --- grouped MFMA GEMM + fused GRU epilogue -------------------------------
// block: 256 thr = 4 waves; chunk of M<=16 batch rows; wave wv covers hidden
// units [y*128 + wv*32, +32) for all 3 gates. B streamed from global (no LDS,
// no K-loop barriers). 3-term split-bf16 MFMA.
__global__ __launch_bounds__(256, 2) void k_gemm_mfma(
    const unsigned short* __restrict__ w3h, const unsigned short* __restrict__ w3l,
    const unsigned short* __restrict__ hxh, const unsigned short* __restrict__ hxl,
    const float* __restrict__ hx, const float4* __restrict__ b4,
    const int* __restrict__ sorted, const int* __restrict__ items,
    const int* __restrict__ nitems, float* __restrict__ out)
{
    int bid = blockIdx.x;
    if (bid >= *nitems) return;
    int item = items[bid];
    int e = item >> 20, base = (item >> 5) & 0xfff, M = item & 31;

    __shared__ unsigned short Ah[16 * 256];
    __shared__ unsigned short Al[16 * 256];
    __shared__ int bids[16];

    int t = threadIdx.x;
    {   // stage A (16 rows x 256 k, bf16 hi/lo), XOR-swizzled 16B chunks
        int row = t >> 4, c16 = t & 15;
        int b = (row < M) ? sorted[base + row] : -1;
        if (c16 == 0) bids[row] = b;
        int col0 = (c16 * 2) ^ (row & 7), col1 = (c16 * 2 + 1) ^ (row & 7);
        if (b >= 0) {
            const uint4* sh = (const uint4*)(hxh + ((size_t)b << 8));
            const uint4* sl = (const uint4*)(hxl + ((size_t)b << 8));
            *(uint4*)&Ah[row * 256 + col0 * 8] = sh[c16 * 2];
            *(uint4*)&Ah[row * 256 + col1 * 8] = sh[c16 * 2 + 1];
            *(uint4*)&Al[row * 256 + col0 * 8] = sl[c16 * 2];
            *(uint4*)&Al[row * 256 + col1 * 8] = sl[c16 * 2 + 1];
        } else {
            uint4 z = {0, 0, 0, 0};
            *(uint4*)&Ah[row * 256 + col0 * 8] = z;
            *(uint4*)&Ah[row * 256 + col1 * 8] = z;
            *(uint4*)&Al[row * 256 + col0 * 8] = z;
            *(uint4*)&Al[row * 256 + col1 * 8] = z;
        }
    }
    __syncthreads();

    int lane = t & 63, wv = t >> 6;
    int m16 = lane & 15, kg = lane >> 4;
    int t0 = blockIdx.y * 128 + wv * 32;

    f32x4_t acc[3][2];
#pragma unroll
    for (int g = 0; g < 3; ++g)
#pragma unroll
        for (int j = 0; j < 2; ++j) acc[g][j] = (f32x4_t){0.f, 0.f, 0.f, 0.f};

    const size_t ebase = (size_t)e * G3 * 256;

    for (int ks = 0; ks < 8; ++ks) {
        int ch = ks * 4 + kg;
        int sw = (ch ^ (m16 & 7)) << 3;
        bf16x8_t a_h = *(const bf16x8_t*)&Ah[m16 * 256 + sw];
        bf16x8_t a_l = *(const bf16x8_t*)&Al[m16 * 256 + sw];
#pragma unroll
        for (int g = 0; g < 3; ++g)
#pragma unroll
            for (int j = 0; j < 2; ++j) {
                size_t off = ebase + (size_t)(g * 256 + t0 + j * 16 + m16) * 256 + ks * 32 + kg * 8;
                bf16x8_t b_h = *(const bf16x8_t*)(w3h + off);
                bf16x8_t b_l = *(const bf16x8_t*)(w3l + off);
                acc[g][j] = __builtin_amdgcn_mfma_f32_16x16x32_bf16(a_h, b_h, acc[g][j], 0, 0, 0);
                acc[g][j] = __builtin_amdgcn_mfma_f32_16x16x32_bf16(a_l, b_h, acc[g][j], 0, 0, 0);
                acc[g][j] = __builtin_amdgcn_mfma_f32_16x16x32_bf16(a_h, b_l, acc[g][j], 0, 0, 0);
            }
    }

    // fused GRU epilogue: C row=(lane>>4)*4+reg (batch m), col=lane&15 (unit)
    int mg = (lane >> 4) * 4;
#pragma unroll
    for (int j = 0; j < 2; ++j) {
        int tt = t0 + j * 16 + m16;
        float4 bs = b4[e * 256 + tt];
#pragma unroll
        for (int i = 0; i < 4; ++i) {
            int mr = mg + i;
            if (mr < M) {
                int b = bids[mr];
                float x = hx[(size_t)b * 256 + tt];
                float r = sigm(acc[0][j][i] + bs.x);
                float u = sigm(acc[1][j][i] + bs.y);
                float n = tanhf(bs.z + r * (acc[2][j][i] + bs.w));
                out[(size_t)b * 256 + tt] = u * x + (1.0f - u) * n;
            }
        }
    }
}

// --- fallback: correct but slow, if ws too small --------------------------
__global__ void k_naive(const float* __restrict__ inp, const float* __restrict__ hx,
                        const float* __restrict__ w, const float* __restrict__ b_ih,
                        const float* __restrict__ b_hh, float* __restrict__ out) {
    int b = blockIdx.x;
    int t = threadIdx.x;
    __shared__ float sx[H_N];
    __shared__ int sidx;
    if (t == 0) {
        int idx = 0;
        for (int i = 0; i < I_N; ++i)
            if (inp[b * I_N + i] > 0.5f) idx = i;
        sidx = idx;
    }
    sx[t] = hx[b * H_N + t];
    __syncthreads();
    int i = sidx;
    float a0 = 0.f, a1 = 0.f, a2 = 0.f;
    for (int h = 0; h < H_N; ++h) {
        float xv = sx[h];
        a0 = fmaf(w[(t * H_N + h) * I_N + i], xv, a0);
        a1 = fmaf(w[((256 + t) * H_N + h) * I_N + i], xv, a1);
        a2 = fmaf(w[((512 + t) * H_N + h) * I_N + i], xv, a2);
    }
    float r = sigm(b_ih[t * I_N + i] + a0 + b_hh[t * I_N + i]);
    float u = sigm(b_ih[(256 + t) * I_N + i] + a1 + b_hh[(256 + t) * I_N + i]);
    float n = tanhf(b_ih[(512 + t) * I_N + i] + r * (a2 + b_hh[(512 + t) * I_N + i]));
    out[b * H_N + t] = u * sx[t] + (1.0f - u) * n;
}

extern "C" void kernel_launch(void* const* d_in, const int* in_sizes, int n_in,
                              void* d_out, int out_size, void* d_ws, size_t ws_size,
                              hipStream_t stream) {
    const float* inp  = (const float*)d_in[0];
    const float* hx   = (const float*)d_in[1];
    const float* w    = (const float*)d_in[2];
    const float* b_ih = (const float*)d_in[3];
    const float* b_hh = (const float*)d_in[4];
    float* out = (float*)d_out;

    if (ws_size < (size_t)WS_NEEDED) {
        k_naive<<<B_N, H_N, 0, stream>>>(inp, hx, w, b_ih, b_hh, out);
        return;
    }

    char* ws = (char*)d_ws;
    int* idx_arr = (int*)(ws + WS_IDX);
    int* cursor  = (int*)(ws + WS_CURSOR);
    int* nitems  = (int*)(ws + WS_NITEMS);
    int* items   = (int*)(ws + WS_ITEMS);
    int* sorted  = (int*)(ws + WS_SORTED);
    float4* b4   = (float4*)(ws + WS_B4);
    unsigned short* hxh = (unsigned short*)(ws + WS_HXH);
    unsigned short* hxl = (unsigned short*)(ws + WS_HXL);
    unsigned short* w3h = (unsigned short*)(ws + WS_W3H);
    unsigned short* w3l = (unsigned short*)(ws + WS_W3L);

    k_idx<<<B_N / 256, 256, 0, stream>>>(inp, idx_arr);
    k_plan<<<1, 512, 0, stream>>>(idx_arr, cursor, nitems, items);
    k_scatter<<<B_N / 256, 256, 0, stream>>>(idx_arr, cursor, sorted);
    k_split_hx<<<1024, 256, 0, stream>>>(hx, hxh, hxl);
    k_bias4<<<32, 256, 0, stream>>>(b_ih, b_hh, b4);
    k_repack<<<dim3(48, 8), 256, 0, stream>>>(w, w3h, w3l);
    k_gemm_mfma<<<dim3(288, 2), 256, 0, stream>>>(w3h, w3l, hxh, hxl, hx, b4,
                                                  sorted, items, nitems, out);
}

// Round 4
// 75.720 us; speedup vs baseline: 1.7937x; 1.0532x over previous
//
#include <hip/hip_runtime.h>
#include <math.h>

#define B_N 4096
#define H_N 256
#define I_N 32
#define G3  768

// slots: 320 affinity slots (8 buckets x 40) + 288 overflow
#define NSLOT_AFF 320
#define NSLOT_TOT 608
#define BKT_CAP   40

// ---- workspace layout (bytes) ----
#define WS_IDX     0               // 4096 ints
#define WS_CURSOR  16384           // 32 ints
#define WS_SLOTS   16640           // 608 ints
#define WS_SORTED  20480           // 4096 ints
#define WS_B4      36864           // 32*256 float4 = 128 KB
#define WS_W3H     167936          // 32*768*256 bf16 = 12 MB
#define WS_W3L     12750848        // 12 MB
#define WS_NEEDED  25333760

typedef __attribute__((ext_vector_type(8))) short bf16x8_t;
typedef __attribute__((ext_vector_type(4))) float f32x4_t;

__device__ __forceinline__ float sigm(float x) { return 1.0f / (1.0f + expf(-x)); }

__device__ __forceinline__ unsigned short bf16r(float f) {
    union { float f; unsigned u; } x; x.f = f;
    unsigned r = (x.u + 0x7fffu + ((x.u >> 16) & 1u)) >> 16;
    return (unsigned short)r;
}
__device__ __forceinline__ float bf16f(unsigned short h) {
    union { unsigned u; float f; } x; x.u = ((unsigned)h) << 16;
    return x.f;
}

// --- one-hot -> expert index ----------------------------------------------
__global__ void k_idx(const float* __restrict__ inp, int* __restrict__ idx_arr) {
    int b = blockIdx.x * blockDim.x + threadIdx.x;
    if (b >= B_N) return;
    const float4* p = (const float4*)(inp + b * I_N);
    int idx = 0;
#pragma unroll
    for (int k = 0; k < 8; ++k) {
        float4 v = p[k];
        if (v.x > 0.5f) idx = k * 4 + 0;
        if (v.y > 0.5f) idx = k * 4 + 1;
        if (v.z > 0.5f) idx = k * 4 + 2;
        if (v.w > 0.5f) idx = k * 4 + 3;
    }
    idx_arr[b] = idx;
}

// --- histogram + prefix + XCD-affine slot plan (1 block) ------------------
// item = (e<<20)|(base<<5)|M. Expert e's chunks land at slots s with s%8==e%8
// so blockIdx%8 (round-robin XCD) keeps each expert's w3 slice in ONE XCD L2.
__global__ void k_plan(const int* __restrict__ idx_arr, int* __restrict__ cursor,
                       int* __restrict__ slots) {
    __shared__ int hist[32], offs_l[32];
    __shared__ int bcur[8], ovf;
    int t = threadIdx.x;
    if (t < 32) hist[t] = 0;
    if (t < 8) bcur[t] = 0;
    if (t == 0) ovf = 0;
    __syncthreads();
    for (int i = t; i < B_N; i += 512) atomicAdd(&hist[idx_arr[i]], 1);
    __syncthreads();
    if (t == 0) {
        int run = 0;
        for (int e = 0; e < 32; ++e) { offs_l[e] = run; run += hist[e]; }
    }
    __syncthreads();
    if (t < 32) cursor[t] = offs_l[t];
    for (int s = t; s < NSLOT_TOT; s += 512) slots[s] = -1;
    __syncthreads();
    for (int c = t; c < 32 * 256; c += 512) {
        int e = c >> 8, ch = c & 255;
        int cnt = hist[e];
        if (ch * 16 < cnt) {
            int M = cnt - ch * 16; if (M > 16) M = 16;
            int base = offs_l[e] + ch * 16;
            int item = (e << 20) | (base << 5) | M;
            int bkt = e & 7;
            int j = atomicAdd(&bcur[bkt], 1);
            if (j < BKT_CAP) slots[bkt + 8 * j] = item;
            else { int k = atomicAdd(&ovf, 1); slots[NSLOT_AFF + k] = item; }
        }
    }
}

// --- scatter batch ids into expert-sorted order ---------------------------
__global__ void k_scatter(const int* __restrict__ idx_arr, int* __restrict__ cursor,
                          int* __restrict__ sorted) {
    int b = blockIdx.x * blockDim.x + threadIdx.x;
    if (b >= B_N) return;
    int i = idx_arr[b];
    int pos = atomicAdd(cursor + i, 1);
    sorted[pos] = b;
}

// --- bias precompute: b4[e][t] = {r_sum, u_sum, n_ih, n_hh} ---------------
__global__ void k_bias4(const float* __restrict__ b_ih, const float* __restrict__ b_hh,
                        float4* __restrict__ b4) {
    int t = threadIdx.x;
    int e = t & 31;
    int tt = blockIdx.x * 8 + (t >> 5);
    float r = b_ih[(0 * 256 + tt) * 32 + e] + b_hh[(0 * 256 + tt) * 32 + e];
    float u = b_ih[(256 + tt) * 32 + e] + b_hh[(256 + tt) * 32 + e];
    float ni = b_ih[(512 + tt) * 32 + e];
    float nh = b_hh[(512 + tt) * 32 + e];
    float4 o = {r, u, ni, nh};
    b4[e * 256 + tt] = o;
}

// --- repack w[g][h][e] -> w3{h,l}[e][n=g][k=h], bf16 hi/lo ----------------
// tile: 8 g x 32 h x 32 e (32.8 KB LDS) -> 768 blocks, ~3 blocks/CU.
__global__ __launch_bounds__(256) void k_repack(const float* __restrict__ w,
                                                unsigned short* __restrict__ w3h,
                                                unsigned short* __restrict__ w3l) {
    __shared__ float tl[8464];    // flat = dg*1058 + hh*33 + e  (<=2-way banks)
    int g0 = blockIdx.x * 8, h0 = blockIdx.y * 32;
    int t = threadIdx.x;
#pragma unroll
    for (int it = 0; it < 8; ++it) {
        int f = (it * 256 + t) * 4;          // 0..8191
        int dg = f >> 10, hh = (f >> 5) & 31, e0 = f & 31;
        float4 v = *(const float4*)(w + ((size_t)(g0 + dg) * 256 + h0 + hh) * 32 + e0);
        int bse = dg * 1058 + hh * 33 + e0;
        tl[bse + 0] = v.x; tl[bse + 1] = v.y; tl[bse + 2] = v.z; tl[bse + 3] = v.w;
    }
    __syncthreads();
#pragma unroll
    for (int a = 0; a < 4; ++a) {
        int idx = a * 256 + t;               // 0..1023
        int q = idx & 3, dg = (idx >> 2) & 7, e = idx >> 5;
        union { unsigned short us[8]; uint4 v; } hi, lo;
#pragma unroll
        for (int jj = 0; jj < 8; ++jj) {
            float f = tl[dg * 1058 + (q * 8 + jj) * 33 + e];
            unsigned short h = bf16r(f);
            hi.us[jj] = h;
            lo.us[jj] = bf16r(f - bf16f(h));
        }
        size_t off = ((size_t)e * G3 + g0 + dg) * 256 + h0 + q * 8;
        *(uint4*)(w3h + off) = hi.v;
        *(uint4*)(w3l + off) = lo.v;
    }
}

// --- grouped MFMA GEMM + fused GRU epilogue -------------------------------
// 4 waves/block, M<=16 rows; wave wv covers units [y*128+wv*32,+32) for all 3
// gates. A staged fp32->bf16 hi/lo in-register into swizzled LDS; B streamed
// from global (XCD-L2-resident via slot affinity). 3-term split-bf16 MFMA.
__global__ __launch_bounds__(256, 2) void k_gemm_mfma(
    const unsigned short* __restrict__ w3h, const unsigned short* __restrict__ w3l,
    const float* __restrict__ hx, const float4* __restrict__ b4,
    const int* __restrict__ sorted, const int* __restrict__ slots,
    float* __restrict__ out)
{
    int item = slots[blockIdx.x];
    if (item < 0) return;
    int e = item >> 20, base = (item >> 5) & 0xfff, M = item & 31;

    __shared__ unsigned short Ah[16 * 256];
    __shared__ unsigned short Al[16 * 256];
    __shared__ int bids[16];

    int t = threadIdx.x;
    {   // stage A: row = t>>4 (batch), c16 = t&15 owns k in [c16*16, +16)
        int row = t >> 4, c16 = t & 15;
        int b = (row < M) ? sorted[base + row] : -1;
        if (c16 == 0) bids[row] = b;
        int col0 = (c16 * 2) ^ (row & 7), col1 = (c16 * 2 + 1) ^ (row & 7);
        union { unsigned short us[8]; uint4 v; } h0u, h1u, l0u, l1u;
        if (b >= 0) {
            const float* src = hx + ((size_t)b << 8) + c16 * 16;
            float fv[16];
            *(float4*)&fv[0]  = *(const float4*)(src);
            *(float4*)&fv[4]  = *(const float4*)(src + 4);
            *(float4*)&fv[8]  = *(const float4*)(src + 8);
            *(float4*)&fv[12] = *(const float4*)(src + 12);
#pragma unroll
            for (int jj = 0; jj < 8; ++jj) {
                unsigned short a = bf16r(fv[jj]);
                h0u.us[jj] = a; l0u.us[jj] = bf16r(fv[jj] - bf16f(a));
                unsigned short c = bf16r(fv[8 + jj]);
                h1u.us[jj] = c; l1u.us[jj] = bf16r(fv[8 + jj] - bf16f(c));
            }
        } else {
            uint4 z = {0, 0, 0, 0};
            h0u.v = z; h1u.v = z; l0u.v = z; l1u.v = z;
        }
        *(uint4*)&Ah[row * 256 + col0 * 8] = h0u.v;
        *(uint4*)&Ah[row * 256 + col1 * 8] = h1u.v;
        *(uint4*)&Al[row * 256 + col0 * 8] = l0u.v;
        *(uint4*)&Al[row * 256 + col1 * 8] = l1u.v;
    }
    __syncthreads();

    int lane = t & 63, wv = t >> 6;
    int m16 = lane & 15, kg = lane >> 4;
    int t0 = blockIdx.y * 128 + wv * 32;

    f32x4_t acc[3][2];
#pragma unroll
    for (int g = 0; g < 3; ++g)
#pragma unroll
        for (int j = 0; j < 2; ++j) acc[g][j] = (f32x4_t){0.f, 0.f, 0.f, 0.f};

    const size_t ebase = (size_t)e * G3 * 256;

    for (int ks = 0; ks < 8; ++ks) {
        int ch = ks * 4 + kg;
        int sw = (ch ^ (m16 & 7)) << 3;
        bf16x8_t a_h = *(const bf16x8_t*)&Ah[m16 * 256 + sw];
        bf16x8_t a_l = *(const bf16x8_t*)&Al[m16 * 256 + sw];
#pragma unroll
        for (int g = 0; g < 3; ++g)
#pragma unroll
            for (int j = 0; j < 2; ++j) {
                size_t off = ebase + (size_t)(g * 256 + t0 + j * 16 + m16) * 256 + ks * 32 + kg * 8;
                bf16x8_t b_h = *(const bf16x8_t*)(w3h + off);
                bf16x8_t b_l = *(const bf16x8_t*)(w3l + off);
                acc[g][j] = __builtin_amdgcn_mfma_f32_16x16x32_bf16(a_h, b_h, acc[g][j], 0, 0, 0);
                acc[g][j] = __builtin_amdgcn_mfma_f32_16x16x32_bf16(a_l, b_h, acc[g][j], 0, 0, 0);
                acc[g][j] = __builtin_amdgcn_mfma_f32_16x16x32_bf16(a_h, b_l, acc[g][j], 0, 0, 0);
            }
    }

    // fused GRU epilogue: C row=(lane>>4)*4+reg (batch m), col=lane&15 (unit)
    int mg = (lane >> 4) * 4;
#pragma unroll
    for (int j = 0; j < 2; ++j) {
        int tt = t0 + j * 16 + m16;
        float4 bs = b4[e * 256 + tt];
#pragma unroll
        for (int i = 0; i < 4; ++i) {
            int mr = mg + i;
            if (mr < M) {
                int b = bids[mr];
                float x = hx[(size_t)b * 256 + tt];
                float r = sigm(acc[0][j][i] + bs.x);
                float u = sigm(acc[1][j][i] + bs.y);
                float n = tanhf(bs.z + r * (acc[2][j][i] + bs.w));
                out[(size_t)b * 256 + tt] = u * x + (1.0f - u) * n;
            }
        }
    }
}

// --- fallback: correct but slow, if ws too small --------------------------
__global__ void k_naive(const float* __restrict__ inp, const float* __restrict__ hx,
                        const float* __restrict__ w, const float* __restrict__ b_ih,
                        const float* __restrict__ b_hh, float* __restrict__ out) {
    int b = blockIdx.x;
    int t = threadIdx.x;
    __shared__ float sx[H_N];
    __shared__ int sidx;
    if (t == 0) {
        int idx = 0;
        for (int i = 0; i < I_N; ++i)
            if (inp[b * I_N + i] > 0.5f) idx = i;
        sidx = idx;
    }
    sx[t] = hx[b * H_N + t];
    __syncthreads();
    int i = sidx;
    float a0 = 0.f, a1 = 0.f, a2 = 0.f;
    for (int h = 0; h < H_N; ++h) {
        float xv = sx[h];
        a0 = fmaf(w[(t * H_N + h) * I_N + i], xv, a0);
        a1 = fmaf(w[((256 + t) * H_N + h) * I_N + i], xv, a1);
        a2 = fmaf(w[((512 + t) * H_N + h) * I_N + i], xv, a2);
    }
    float r = sigm(b_ih[t * I_N + i] + a0 + b_hh[t * I_N + i]);
    float u = sigm(b_ih[(256 + t) * I_N + i] + a1 + b_hh[(256 + t) * I_N + i]);
    float n = tanhf(b_ih[(512 + t) * I_N + i] + r * (a2 + b_hh[(512 + t) * I_N + i]));
    out[b * H_N + t] = u * sx[t] + (1.0f - u) * n;
}

extern "C" void kernel_launch(void* const* d_in, const int* in_sizes, int n_in,
                              void* d_out, int out_size, void* d_ws, size_t ws_size,
                              hipStream_t stream) {
    const float* inp  = (const float*)d_in[0];
    const float* hx   = (const float*)d_in[1];
    const float* w    = (const float*)d_in[2];
    const float* b_ih = (const float*)d_in[3];
    const float* b_hh = (const float*)d_in[4];
    float* out = (float*)d_out;

    if (ws_size < (size_t)WS_NEEDED) {
        k_naive<<<B_N, H_N, 0, stream>>>(inp, hx, w, b_ih, b_hh, out);
        return;
    }

    char* ws = (char*)d_ws;
    int* idx_arr = (int*)(ws + WS_IDX);
    int* cursor  = (int*)(ws + WS_CURSOR);
    int* slots   = (int*)(ws + WS_SLOTS);
    int* sorted  = (int*)(ws + WS_SORTED);
    float4* b4   = (float4*)(ws + WS_B4);
    unsigned short* w3h = (unsigned short*)(ws + WS_W3H);
    unsigned short* w3l = (unsigned short*)(ws + WS_W3L);

    k_idx<<<B_N / 256, 256, 0, stream>>>(inp, idx_arr);
    k_plan<<<1, 512, 0, stream>>>(idx_arr, cursor, slots);
    k_scatter<<<B_N / 256, 256, 0, stream>>>(idx_arr, cursor, sorted);
    k_bias4<<<32, 256, 0, stream>>>(b_ih, b_hh, b4);
    k_repack<<<dim3(96, 8), 256, 0, stream>>>(w, w3h, w3l);
    k_gemm_mfma<<<dim3(NSLOT_TOT, 2), 256, 0, stream>>>(w3h, w3l, hx, b4,
                                                        sorted, slots, out);
}

// Round 5
// 51.788 us; speedup vs baseline: 2.6226x; 1.4621x over previous
//
#include <hip/hip_runtime.h>
#include <math.h>

#define B_N 4096
#define H_N 256
#define I_N 32
#define G3  768

// slots: 320 affinity slots (8 buckets x 40) + 288 overflow
#define NSLOT_AFF 320
#define NSLOT_TOT 608
#define BKT_CAP   40

// ---- workspace layout (bytes) ----
#define WS_IDX     0               // 4096 ints
#define WS_CURSOR  16384           // 32 ints
#define WS_SLOTS   16640           // 608 ints
#define WS_SORTED  20480           // 4096 ints
#define WS_B4      36864           // 32*256 float4 = 128 KB
#define WS_W5H     167936          // 32*768*256 bf16 = 12 MB (fragment-major)
#define WS_W5L     12750848        // 12 MB
#define WS_NEEDED  25333760

typedef __attribute__((ext_vector_type(8))) short bf16x8_t;
typedef __attribute__((ext_vector_type(4))) float f32x4_t;

__device__ __forceinline__ float sigm(float x) { return 1.0f / (1.0f + expf(-x)); }

__device__ __forceinline__ unsigned short bf16r(float f) {
    union { float f; unsigned u; } x; x.f = f;
    unsigned r = (x.u + 0x7fffu + ((x.u >> 16) & 1u)) >> 16;
    return (unsigned short)r;
}
__device__ __forceinline__ float bf16f(unsigned short h) {
    union { unsigned u; float f; } x; x.u = ((unsigned)h) << 16;
    return x.f;
}

// --- one-hot -> expert index ----------------------------------------------
__global__ void k_idx(const float* __restrict__ inp, int* __restrict__ idx_arr) {
    int b = blockIdx.x * blockDim.x + threadIdx.x;
    if (b >= B_N) return;
    const float4* p = (const float4*)(inp + b * I_N);
    int idx = 0;
#pragma unroll
    for (int k = 0; k < 8; ++k) {
        float4 v = p[k];
        if (v.x > 0.5f) idx = k * 4 + 0;
        if (v.y > 0.5f) idx = k * 4 + 1;
        if (v.z > 0.5f) idx = k * 4 + 2;
        if (v.w > 0.5f) idx = k * 4 + 3;
    }
    idx_arr[b] = idx;
}

// --- histogram + prefix + XCD-affine slot plan (1 block) ------------------
// item = (e<<20)|(base<<5)|M. Expert e's chunks land at slots s with s%8==e%8
// so blockIdx%8 (round-robin XCD) keeps each expert's w5 slice in ONE XCD L2.
__global__ void k_plan(const int* __restrict__ idx_arr, int* __restrict__ cursor,
                       int* __restrict__ slots) {
    __shared__ int hist[32], offs_l[32];
    __shared__ int bcur[8], ovf;
    int t = threadIdx.x;
    if (t < 32) hist[t] = 0;
    if (t < 8) bcur[t] = 0;
    if (t == 0) ovf = 0;
    __syncthreads();
    for (int i = t; i < B_N; i += 512) atomicAdd(&hist[idx_arr[i]], 1);
    __syncthreads();
    if (t == 0) {
        int run = 0;
        for (int e = 0; e < 32; ++e) { offs_l[e] = run; run += hist[e]; }
    }
    __syncthreads();
    if (t < 32) cursor[t] = offs_l[t];
    for (int s = t; s < NSLOT_TOT; s += 512) slots[s] = -1;
    __syncthreads();
    for (int c = t; c < 32 * 256; c += 512) {
        int e = c >> 8, ch = c & 255;
        int cnt = hist[e];
        if (ch * 16 < cnt) {
            int M = cnt - ch * 16; if (M > 16) M = 16;
            int base = offs_l[e] + ch * 16;
            int item = (e << 20) | (base << 5) | M;
            int bkt = e & 7;
            int j = atomicAdd(&bcur[bkt], 1);
            if (j < BKT_CAP) slots[bkt + 8 * j] = item;
            else { int k = atomicAdd(&ovf, 1); slots[NSLOT_AFF + k] = item; }
        }
    }
}

// --- fused aux kernel: repack (768) | bias4 (32) | scatter (16) -----------
// repack: w[g3][h][e] fp32 -> fragment-major bf16 hi/lo:
//   w5[e][ks(8)][rowgrp(48)][lane(64)] as uint4; lane = kg*16+m16 holds
//   row = rowgrp*16+m16, k = ks*32+kg*8+0..7.  Each MFMA B-fragment is a
//   contiguous 1 KB block read as lane-consecutive dwordx4 (no gather!).
__global__ __launch_bounds__(256) void k_aux(
    const float* __restrict__ w, unsigned short* __restrict__ w5h,
    unsigned short* __restrict__ w5l,
    const float* __restrict__ b_ih, const float* __restrict__ b_hh,
    float4* __restrict__ b4,
    const int* __restrict__ idx_arr, int* __restrict__ cursor,
    int* __restrict__ sorted)
{
    int bid = blockIdx.x;
    int t = threadIdx.x;
    if (bid < 768) {
        // ---- repack: 8 g3-rows x 32 h x 32 e per block ----
        __shared__ float tl[8 * 1057];      // row stride 1057 (odd): bank-spread
        int r0 = (bid >> 3) * 8;            // g3-row base (0..760)
        int ks = bid & 7;                   // h-tile = ks*32
#pragma unroll
        for (int it = 0; it < 8; ++it) {
            int f4 = it * 256 + t;          // 0..2047
            int e4 = (f4 & 7) * 4, hh = (f4 >> 3) & 31, r = f4 >> 8;
            float4 v = *(const float4*)(w + ((size_t)(r0 + r) * 256 + ks * 32 + hh) * 32 + e4);
            int bse = r * 1057 + hh * 33 + e4;
            tl[bse] = v.x; tl[bse + 1] = v.y; tl[bse + 2] = v.z; tl[bse + 3] = v.w;
        }
        __syncthreads();
        int rowgrp = r0 >> 4;
        int mbase = r0 & 15;                // 0 or 8
#pragma unroll
        for (int it = 0; it < 4; ++it) {
            int c = it * 256 + t;           // 0..1023
            int m8 = c & 7, kg = (c >> 3) & 3, e = c >> 5;
            union { unsigned short us[8]; uint4 v; } hi, lo;
#pragma unroll
            for (int t8 = 0; t8 < 8; ++t8) {
                float f = tl[m8 * 1057 + (kg * 8 + t8) * 33 + e];
                unsigned short h = bf16r(f);
                hi.us[t8] = h; lo.us[t8] = bf16r(f - bf16f(h));
            }
            size_t chunk = ((size_t)(e * 8 + ks) * 48 + rowgrp) * 64 + kg * 16 + mbase + m8;
            ((uint4*)w5h)[chunk] = hi.v;
            ((uint4*)w5l)[chunk] = lo.v;
        }
    } else if (bid < 800) {
        // ---- bias4: b4[e][tt] = {r_sum, u_sum, n_ih, n_hh} ----
        int bb = bid - 768;
        int e = t & 31;
        int tt = bb * 8 + (t >> 5);
        float r = b_ih[tt * 32 + e] + b_hh[tt * 32 + e];
        float u = b_ih[(256 + tt) * 32 + e] + b_hh[(256 + tt) * 32 + e];
        float ni = b_ih[(512 + tt) * 32 + e];
        float nh = b_hh[(512 + tt) * 32 + e];
        float4 o = {r, u, ni, nh};
        b4[e * 256 + tt] = o;
    } else {
        // ---- scatter ----
        int b = (bid - 800) * 256 + t;
        if (b < B_N) {
            int i = idx_arr[b];
            int pos = atomicAdd(cursor + i, 1);
            sorted[pos] = b;
        }
    }
}

// --- grouped MFMA GEMM + fused GRU epilogue -------------------------------
// 4 waves/block, M<=16 rows; wave wv covers units [y*128+wv*32,+32) x 3
// gates. A staged fp32->bf16 hi/lo in LDS; B read as contiguous 1 KB
// fragment streams (fragment-major layout), no K-loop barriers, full unroll.
__global__ __launch_bounds__(256, 2) void k_gemm_mfma(
    const unsigned short* __restrict__ w5h, const unsigned short* __restrict__ w5l,
    const float* __restrict__ hx, const float4* __restrict__ b4,
    const int* __restrict__ sorted, const int* __restrict__ slots,
    float* __restrict__ out)
{
    int item = slots[blockIdx.x];
    if (item < 0) return;
    int e = item >> 20, base = (item >> 5) & 0xfff, M = item & 31;

    __shared__ unsigned short Ah[16 * 256];
    __shared__ unsigned short Al[16 * 256];
    __shared__ int bids[16];

    int t = threadIdx.x;
    {   // stage A: row = t>>4 (batch), c16 = t&15 owns k in [c16*16, +16)
        int row = t >> 4, c16 = t & 15;
        int b = (row < M) ? sorted[base + row] : -1;
        if (c16 == 0) bids[row] = b;
        int col0 = (c16 * 2) ^ (row & 7), col1 = (c16 * 2 + 1) ^ (row & 7);
        union { unsigned short us[8]; uint4 v; } h0u, h1u, l0u, l1u;
        if (b >= 0) {
            const float* src = hx + ((size_t)b << 8) + c16 * 16;
            float fv[16];
            *(float4*)&fv[0]  = *(const float4*)(src);
            *(float4*)&fv[4]  = *(const float4*)(src + 4);
            *(float4*)&fv[8]  = *(const float4*)(src + 8);
            *(float4*)&fv[12] = *(const float4*)(src + 12);
#pragma unroll
            for (int jj = 0; jj < 8; ++jj) {
                unsigned short a = bf16r(fv[jj]);
                h0u.us[jj] = a; l0u.us[jj] = bf16r(fv[jj] - bf16f(a));
                unsigned short c = bf16r(fv[8 + jj]);
                h1u.us[jj] = c; l1u.us[jj] = bf16r(fv[8 + jj] - bf16f(c));
            }
        } else {
            uint4 z = {0, 0, 0, 0};
            h0u.v = z; h1u.v = z; l0u.v = z; l1u.v = z;
        }
        *(uint4*)&Ah[row * 256 + col0 * 8] = h0u.v;
        *(uint4*)&Ah[row * 256 + col1 * 8] = h1u.v;
        *(uint4*)&Al[row * 256 + col0 * 8] = l0u.v;
        *(uint4*)&Al[row * 256 + col1 * 8] = l1u.v;
    }
    __syncthreads();

    int lane = t & 63, wv = t >> 6;
    int m16 = lane & 15, kg = lane >> 4;
    int y = blockIdx.y;
    int t0 = y * 128 + wv * 32;

    f32x4_t acc[3][2];
#pragma unroll
    for (int g = 0; g < 3; ++g)
#pragma unroll
        for (int j = 0; j < 2; ++j) acc[g][j] = (f32x4_t){0.f, 0.f, 0.f, 0.f};

    // fragment-major: frag id = (e*8+ks)*48 + g*16 + y*8 + wv*2 + j, 512 ush each
    const size_t wbase = ((size_t)e * 8) * 48 * 512 + (size_t)(y * 8 + wv * 2) * 512 + (size_t)lane * 8;
    const unsigned short* bh_p = w5h + wbase;
    const unsigned short* bl_p = w5l + wbase;

#pragma unroll
    for (int ks = 0; ks < 8; ++ks) {
        int ch = ks * 4 + kg;
        int sw = (ch ^ (m16 & 7)) << 3;
        bf16x8_t a_h = *(const bf16x8_t*)&Ah[m16 * 256 + sw];
        bf16x8_t a_l = *(const bf16x8_t*)&Al[m16 * 256 + sw];
#pragma unroll
        for (int g = 0; g < 3; ++g)
#pragma unroll
            for (int j = 0; j < 2; ++j) {
                size_t foff = ((size_t)ks * 48 + g * 16 + j) * 512;
                bf16x8_t b_h = *(const bf16x8_t*)(bh_p + foff);
                bf16x8_t b_l = *(const bf16x8_t*)(bl_p + foff);
                acc[g][j] = __builtin_amdgcn_mfma_f32_16x16x32_bf16(a_h, b_h, acc[g][j], 0, 0, 0);
                acc[g][j] = __builtin_amdgcn_mfma_f32_16x16x32_bf16(a_l, b_h, acc[g][j], 0, 0, 0);
                acc[g][j] = __builtin_amdgcn_mfma_f32_16x16x32_bf16(a_h, b_l, acc[g][j], 0, 0, 0);
            }
    }

    // fused GRU epilogue: C row=(lane>>4)*4+reg (batch m), col=lane&15 (unit)
    int mg = (lane >> 4) * 4;
#pragma unroll
    for (int j = 0; j < 2; ++j) {
        int tt = t0 + j * 16 + m16;
        float4 bs = b4[e * 256 + tt];
#pragma unroll
        for (int i = 0; i < 4; ++i) {
            int mr = mg + i;
            if (mr < M) {
                int b = bids[mr];
                float x = hx[(size_t)b * 256 + tt];
                float r = sigm(acc[0][j][i] + bs.x);
                float u = sigm(acc[1][j][i] + bs.y);
                float n = tanhf(bs.z + r * (acc[2][j][i] + bs.w));
                out[(size_t)b * 256 + tt] = u * x + (1.0f - u) * n;
            }
        }
    }
}

// --- fallback: correct but slow, if ws too small --------------------------
__global__ void k_naive(const float* __restrict__ inp, const float* __restrict__ hx,
                        const float* __restrict__ w, const float* __restrict__ b_ih,
                        const float* __restrict__ b_hh, float* __restrict__ out) {
    int b = blockIdx.x;
    int t = threadIdx.x;
    __shared__ float sx[H_N];
    __shared__ int sidx;
    if (t == 0) {
        int idx = 0;
        for (int i = 0; i < I_N; ++i)
            if (inp[b * I_N + i] > 0.5f) idx = i;
        sidx = idx;
    }
    sx[t] = hx[b * H_N + t];
    __syncthreads();
    int i = sidx;
    float a0 = 0.f, a1 = 0.f, a2 = 0.f;
    for (int h = 0; h < H_N; ++h) {
        float xv = sx[h];
        a0 = fmaf(w[(t * H_N + h) * I_N + i], xv, a0);
        a1 = fmaf(w[((256 + t) * H_N + h) * I_N + i], xv, a1);
        a2 = fmaf(w[((512 + t) * H_N + h) * I_N + i], xv, a2);
    }
    float r = sigm(b_ih[t * I_N + i] + a0 + b_hh[t * I_N + i]);
    float u = sigm(b_ih[(256 + t) * I_N + i] + a1 + b_hh[(256 + t) * I_N + i]);
    float n = tanhf(b_ih[(512 + t) * I_N + i] + r * (a2 + b_hh[(512 + t) * I_N + i]));
    out[b * H_N + t] = u * sx[t] + (1.0f - u) * n;
}

extern "C" void kernel_launch(void* const* d_in, const int* in_sizes, int n_in,
                              void* d_out, int out_size, void* d_ws, size_t ws_size,
                              hipStream_t stream) {
    const float* inp  = (const float*)d_in[0];
    const float* hx   = (const float*)d_in[1];
    const float* w    = (const float*)d_in[2];
    const float* b_ih = (const float*)d_in[3];
    const float* b_hh = (const float*)d_in[4];
    float* out = (float*)d_out;

    if (ws_size < (size_t)WS_NEEDED) {
        k_naive<<<B_N, H_N, 0, stream>>>(inp, hx, w, b_ih, b_hh, out);
        return;
    }

    char* ws = (char*)d_ws;
    int* idx_arr = (int*)(ws + WS_IDX);
    int* cursor  = (int*)(ws + WS_CURSOR);
    int* slots   = (int*)(ws + WS_SLOTS);
    int* sorted  = (int*)(ws + WS_SORTED);
    float4* b4   = (float4*)(ws + WS_B4);
    unsigned short* w5h = (unsigned short*)(ws + WS_W5H);
    unsigned short* w5l = (unsigned short*)(ws + WS_W5L);

    k_idx<<<B_N / 256, 256, 0, stream>>>(inp, idx_arr);
    k_plan<<<1, 512, 0, stream>>>(idx_arr, cursor, slots);
    k_aux<<<816, 256, 0, stream>>>(w, w5h, w5l, b_ih, b_hh, b4, idx_arr, cursor, sorted);
    k_gemm_mfma<<<dim3(NSLOT_TOT, 2), 256, 0, stream>>>(w5h, w5l, hx, b4,
                                                        sorted, slots, out);
}

// Round 6
// 43.954 us; speedup vs baseline: 3.0900x; 1.1782x over previous
//
#include <hip/hip_runtime.h>
#include <math.h>

#define B_N 4096
#define H_N 256
#define I_N 32
#define G3  768

// slots: 192 affinity slots (8 buckets x 24) + 144 overflow; 336 % 8 == 0
#define NSLOT_AFF 192
#define NSLOT_TOT 336
#define BKT_CAP   24

// ---- workspace layout (bytes) ----
#define WS_IDX     0               // 4096 ints
#define WS_SLOTS   16640           // 336 ints
#define WS_SORTED  20480           // 4096 ints
#define WS_B4      36864           // 32*256 float4 = 128 KB
#define WS_W5H     167936          // 32*768*256 bf16 = 12 MB (fragment-major)
#define WS_W5L     12750848        // 12 MB
#define WS_NEEDED  25333760

typedef __attribute__((ext_vector_type(8))) short bf16x8_t;
typedef __attribute__((ext_vector_type(4))) float f32x4_t;

__device__ __forceinline__ float sigm(float x) { return 1.0f / (1.0f + expf(-x)); }

__device__ __forceinline__ unsigned short bf16r(float f) {
    union { float f; unsigned u; } x; x.f = f;
    unsigned r = (x.u + 0x7fffu + ((x.u >> 16) & 1u)) >> 16;
    return (unsigned short)r;
}
__device__ __forceinline__ float bf16f(unsigned short h) {
    union { unsigned u; float f; } x; x.u = ((unsigned)h) << 16;
    return x.f;
}

// --- one-hot -> expert index ----------------------------------------------
__global__ void k_idx(const float* __restrict__ inp, int* __restrict__ idx_arr) {
    int b = blockIdx.x * blockDim.x + threadIdx.x;
    if (b >= B_N) return;
    const float4* p = (const float4*)(inp + b * I_N);
    int idx = 0;
#pragma unroll
    for (int k = 0; k < 8; ++k) {
        float4 v = p[k];
        if (v.x > 0.5f) idx = k * 4 + 0;
        if (v.y > 0.5f) idx = k * 4 + 1;
        if (v.z > 0.5f) idx = k * 4 + 2;
        if (v.w > 0.5f) idx = k * 4 + 3;
    }
    idx_arr[b] = idx;
}

// --- histogram + prefix + XCD-affine M=32 chunk plan + scatter (1 block) --
// item = (e<<18)|(base<<6)|M, M<=32. Expert e's chunks at slots s%8==e%8 so
// blockIdx%8 (round-robin XCD) keeps each expert's w5 slice in ONE XCD L2.
__global__ void k_plan(const int* __restrict__ idx_arr, int* __restrict__ slots,
                       int* __restrict__ sorted) {
    __shared__ int hist[32], offs_l[32], lcur[32];
    __shared__ int bcur[8], ovf;
    int t = threadIdx.x;
    if (t < 32) hist[t] = 0;
    if (t < 8) bcur[t] = 0;
    if (t == 0) ovf = 0;
    __syncthreads();
    for (int i = t; i < B_N; i += 512) atomicAdd(&hist[idx_arr[i]], 1);
    __syncthreads();
    if (t == 0) {
        int run = 0;
        for (int e = 0; e < 32; ++e) { offs_l[e] = run; run += hist[e]; }
    }
    __syncthreads();
    if (t < 32) lcur[t] = offs_l[t];
    for (int s = t; s < NSLOT_TOT; s += 512) slots[s] = -1;
    __syncthreads();
    // chunk plan (M=32)
    for (int c = t; c < 32 * 128; c += 512) {
        int e = c >> 7, ch = c & 127;
        int cnt = hist[e];
        if (ch * 32 < cnt) {
            int M = cnt - ch * 32; if (M > 32) M = 32;
            int base = offs_l[e] + ch * 32;
            int item = (e << 18) | (base << 6) | M;
            int bkt = e & 7;
            int j = atomicAdd(&bcur[bkt], 1);
            if (j < BKT_CAP) slots[bkt + 8 * j] = item;
            else { int k = atomicAdd(&ovf, 1); slots[NSLOT_AFF + k] = item; }
        }
    }
    // scatter into expert-sorted order
    for (int b = t; b < B_N; b += 512) {
        int e = idx_arr[b];
        int pos = atomicAdd(&lcur[e], 1);
        sorted[pos] = b;
    }
}

// --- fused aux kernel: repack (768 blocks) | bias4 (32 blocks) ------------
// repack: w[g3][h][e] fp32 -> fragment-major bf16 hi/lo:
//   w5[(e*8+ks)*48 + rowgrp][lane] as uint4; lane = kg*16+m16 holds
//   row = rowgrp*16+m16, k = ks*32+kg*8+0..7.  Each MFMA B-fragment is a
//   contiguous 1 KB block read as lane-consecutive dwordx4 (no gather).
__global__ __launch_bounds__(256) void k_aux(
    const float* __restrict__ w, unsigned short* __restrict__ w5h,
    unsigned short* __restrict__ w5l,
    const float* __restrict__ b_ih, const float* __restrict__ b_hh,
    float4* __restrict__ b4)
{
    int bid = blockIdx.x;
    int t = threadIdx.x;
    if (bid < 768) {
        // ---- repack: 8 g3-rows x 32 h x 32 e per block ----
        __shared__ float tl[8 * 1057];      // odd row stride: bank-spread
        int r0 = (bid >> 3) * 8;            // g3-row base (0..760)
        int ks = bid & 7;                   // h-tile = ks*32
#pragma unroll
        for (int it = 0; it < 8; ++it) {
            int f4 = it * 256 + t;          // 0..2047
            int e4 = (f4 & 7) * 4, hh = (f4 >> 3) & 31, r = f4 >> 8;
            float4 v = *(const float4*)(w + ((size_t)(r0 + r) * 256 + ks * 32 + hh) * 32 + e4);
            int bse = r * 1057 + hh * 33 + e4;
            tl[bse] = v.x; tl[bse + 1] = v.y; tl[bse + 2] = v.z; tl[bse + 3] = v.w;
        }
        __syncthreads();
        int rowgrp = r0 >> 4;
        int mbase = r0 & 15;                // 0 or 8
#pragma unroll
        for (int it = 0; it < 4; ++it) {
            int c = it * 256 + t;           // 0..1023
            int m8 = c & 7, kg = (c >> 3) & 3, e = c >> 5;
            union { unsigned short us[8]; uint4 v; } hi, lo;
#pragma unroll
            for (int t8 = 0; t8 < 8; ++t8) {
                float f = tl[m8 * 1057 + (kg * 8 + t8) * 33 + e];
                unsigned short h = bf16r(f);
                hi.us[t8] = h; lo.us[t8] = bf16r(f - bf16f(h));
            }
            size_t chunk = ((size_t)(e * 8 + ks) * 48 + rowgrp) * 64 + kg * 16 + mbase + m8;
            ((uint4*)w5h)[chunk] = hi.v;
            ((uint4*)w5l)[chunk] = lo.v;
        }
    } else {
        // ---- bias4: b4[e][tt] = {r_sum, u_sum, n_ih, n_hh} ----
        int bb = bid - 768;
        int e = t & 31;
        int tt = bb * 8 + (t >> 5);
        float r = b_ih[tt * 32 + e] + b_hh[tt * 32 + e];
        float u = b_ih[(256 + tt) * 32 + e] + b_hh[(256 + tt) * 32 + e];
        float ni = b_ih[(512 + tt) * 32 + e];
        float nh = b_hh[(512 + tt) * 32 + e];
        float4 o = {r, u, ni, nh};
        b4[e * 256 + tt] = o;
    }
}

// --- grouped MFMA GEMM + fused GRU epilogue, M=32 -------------------------
// 4 waves/block; wave wv covers unit group q = blockIdx.y*4+wv (16 units) x 3
// gates x 2 A-tiles. A staged fp32->bf16 hi/lo in swizzled LDS; B read as
// contiguous 1 KB fragment streams; each fragment feeds 2 A-tiles (2x reuse).
__global__ __launch_bounds__(256) void k_gemm_mfma(
    const unsigned short* __restrict__ w5h, const unsigned short* __restrict__ w5l,
    const float* __restrict__ hx, const float4* __restrict__ b4,
    const int* __restrict__ sorted, const int* __restrict__ slots,
    float* __restrict__ out)
{
    int item = slots[blockIdx.x];
    if (item < 0) return;
    int e = item >> 18, base = (item >> 6) & 0xfff, M = item & 63;

    __shared__ unsigned short Ah[32 * 256];
    __shared__ unsigned short Al[32 * 256];
    __shared__ int bids[32];

    int t = threadIdx.x;
    {   // stage A: row = t>>3 (0..31), c8 = t&7 owns k in [c8*32, +32)
        int row = t >> 3, c8 = t & 7;
        int b = (row < M) ? sorted[base + row] : -1;
        if (c8 == 0) bids[row] = b;
        if (b >= 0) {
            const float* src = hx + ((size_t)b << 8) + c8 * 32;
            float fv[32];
#pragma unroll
            for (int p = 0; p < 8; ++p)
                *(float4*)&fv[p * 4] = *(const float4*)(src + p * 4);
#pragma unroll
            for (int p = 0; p < 4; ++p) {
                union { unsigned short us[8]; uint4 v; } hu, lu;
#pragma unroll
                for (int jj = 0; jj < 8; ++jj) {
                    float f = fv[p * 8 + jj];
                    unsigned short h = bf16r(f);
                    hu.us[jj] = h; lu.us[jj] = bf16r(f - bf16f(h));
                }
                int col = (c8 * 4 + p) ^ (row & 7);
                *(uint4*)&Ah[row * 256 + col * 8] = hu.v;
                *(uint4*)&Al[row * 256 + col * 8] = lu.v;
            }
        } else {
            uint4 z = {0, 0, 0, 0};
#pragma unroll
            for (int p = 0; p < 4; ++p) {
                int col = (c8 * 4 + p) ^ (row & 7);
                *(uint4*)&Ah[row * 256 + col * 8] = z;
                *(uint4*)&Al[row * 256 + col * 8] = z;
            }
        }
    }
    __syncthreads();

    int lane = t & 63, wv = t >> 6;
    int m16 = lane & 15, kg = lane >> 4;
    int q = blockIdx.y * 4 + wv;         // unit group 0..15

    f32x4_t acc[2][3];
#pragma unroll
    for (int tl2 = 0; tl2 < 2; ++tl2)
#pragma unroll
        for (int g = 0; g < 3; ++g) acc[tl2][g] = (f32x4_t){0.f, 0.f, 0.f, 0.f};

    // fragment id = (e*8+ks)*48 + g*16 + q; 512 ush per fragment
    const unsigned short* bh_p = w5h + ((size_t)(e * 8) * 48 + q) * 512 + (size_t)lane * 8;
    const unsigned short* bl_p = w5l + ((size_t)(e * 8) * 48 + q) * 512 + (size_t)lane * 8;

#pragma unroll
    for (int ks = 0; ks < 8; ++ks) {
        int ch = ks * 4 + kg;
        int sw = (ch ^ (m16 & 7)) << 3;
        bf16x8_t a_h0 = *(const bf16x8_t*)&Ah[m16 * 256 + sw];
        bf16x8_t a_l0 = *(const bf16x8_t*)&Al[m16 * 256 + sw];
        bf16x8_t a_h1 = *(const bf16x8_t*)&Ah[(16 + m16) * 256 + sw];
        bf16x8_t a_l1 = *(const bf16x8_t*)&Al[(16 + m16) * 256 + sw];
#pragma unroll
        for (int g = 0; g < 3; ++g) {
            size_t foff = ((size_t)ks * 48 + g * 16) * 512;
            bf16x8_t b_h = *(const bf16x8_t*)(bh_p + foff);
            bf16x8_t b_l = *(const bf16x8_t*)(bl_p + foff);
            acc[0][g] = __builtin_amdgcn_mfma_f32_16x16x32_bf16(a_h0, b_h, acc[0][g], 0, 0, 0);
            acc[0][g] = __builtin_amdgcn_mfma_f32_16x16x32_bf16(a_l0, b_h, acc[0][g], 0, 0, 0);
            acc[0][g] = __builtin_amdgcn_mfma_f32_16x16x32_bf16(a_h0, b_l, acc[0][g], 0, 0, 0);
            acc[1][g] = __builtin_amdgcn_mfma_f32_16x16x32_bf16(a_h1, b_h, acc[1][g], 0, 0, 0);
            acc[1][g] = __builtin_amdgcn_mfma_f32_16x16x32_bf16(a_l1, b_h, acc[1][g], 0, 0, 0);
            acc[1][g] = __builtin_amdgcn_mfma_f32_16x16x32_bf16(a_h1, b_l, acc[1][g], 0, 0, 0);
        }
    }

    // fused GRU epilogue: C row=(lane>>4)*4+reg (batch m), col=lane&15 (unit)
    int mg = (lane >> 4) * 4;
    int tt = q * 16 + m16;
    float4 bs = b4[e * 256 + tt];
#pragma unroll
    for (int tl2 = 0; tl2 < 2; ++tl2) {
#pragma unroll
        for (int i = 0; i < 4; ++i) {
            int mr = tl2 * 16 + mg + i;
            if (mr < M) {
                int b = bids[mr];
                float x = hx[(size_t)b * 256 + tt];
                float r = sigm(acc[tl2][0][i] + bs.x);
                float u = sigm(acc[tl2][1][i] + bs.y);
                float n = tanhf(bs.z + r * (acc[tl2][2][i] + bs.w));
                out[(size_t)b * 256 + tt] = u * x + (1.0f - u) * n;
            }
        }
    }
}

// --- fallback: correct but slow, if ws too small --------------------------
__global__ void k_naive(const float* __restrict__ inp, const float* __restrict__ hx,
                        const float* __restrict__ w, const float* __restrict__ b_ih,
                        const float* __restrict__ b_hh, float* __restrict__ out) {
    int b = blockIdx.x;
    int t = threadIdx.x;
    __shared__ float sx[H_N];
    __shared__ int sidx;
    if (t == 0) {
        int idx = 0;
        for (int i = 0; i < I_N; ++i)
            if (inp[b * I_N + i] > 0.5f) idx = i;
        sidx = idx;
    }
    sx[t] = hx[b * H_N + t];
    __syncthreads();
    int i = sidx;
    float a0 = 0.f, a1 = 0.f, a2 = 0.f;
    for (int h = 0; h < H_N; ++h) {
        float xv = sx[h];
        a0 = fmaf(w[(t * H_N + h) * I_N + i], xv, a0);
        a1 = fmaf(w[((256 + t) * H_N + h) * I_N + i], xv, a1);
        a2 = fmaf(w[((512 + t) * H_N + h) * I_N + i], xv, a2);
    }
    float r = sigm(b_ih[t * I_N + i] + a0 + b_hh[t * I_N + i]);
    float u = sigm(b_ih[(256 + t) * I_N + i] + a1 + b_hh[(256 + t) * I_N + i]);
    float n = tanhf(b_ih[(512 + t) * I_N + i] + r * (a2 + b_hh[(512 + t) * I_N + i]));
    out[b * H_N + t] = u * sx[t] + (1.0f - u) * n;
}

extern "C" void kernel_launch(void* const* d_in, const int* in_sizes, int n_in,
                              void* d_out, int out_size, void* d_ws, size_t ws_size,
                              hipStream_t stream) {
    const float* inp  = (const float*)d_in[0];
    const float* hx   = (const float*)d_in[1];
    const float* w    = (const float*)d_in[2];
    const float* b_ih = (const float*)d_in[3];
    const float* b_hh = (const float*)d_in[4];
    float* out = (float*)d_out;

    if (ws_size < (size_t)WS_NEEDED) {
        k_naive<<<B_N, H_N, 0, stream>>>(inp, hx, w, b_ih, b_hh, out);
        return;
    }

    char* ws = (char*)d_ws;
    int* idx_arr = (int*)(ws + WS_IDX);
    int* slots   = (int*)(ws + WS_SLOTS);
    int* sorted  = (int*)(ws + WS_SORTED);
    float4* b4   = (float4*)(ws + WS_B4);
    unsigned short* w5h = (unsigned short*)(ws + WS_W5H);
    unsigned short* w5l = (unsigned short*)(ws + WS_W5L);

    k_idx<<<B_N / 256, 256, 0, stream>>>(inp, idx_arr);
    k_plan<<<1, 512, 0, stream>>>(idx_arr, slots, sorted);
    k_aux<<<800, 256, 0, stream>>>(w, w5h, w5l, b_ih, b_hh, b4);
    k_gemm_mfma<<<dim3(NSLOT_TOT, 4), 256, 0, stream>>>(w5h, w5l, hx, b4,
                                                        sorted, slots, out);
}